// Round 2
// baseline (326.783 us; speedup 1.0000x reference)
//
#include <hip/hip_runtime.h>
#include <hip/hip_bf16.h>
#include <math.h>

#define N_NODES  8192
#define N_EDGES  49152
#define E_TOT    57344   // edges + self-loops
#define IN_F     128
#define HID      64
#define NH1      64
#define NH2      5
#define OUT_F    32
#define F1       4096    // NH1*HID
#define F2       160     // NH2*OUT_F
#define N_BONDS  64
#define ET       16      // aggx edge-tile
#define NP       8       // head-group partials for fused gemm12 (512 blocks = 2/CU)
#define HG       8       // heads per group = NH1/NP

typedef short bf16x8 __attribute__((ext_vector_type(8)));
typedef short bf16x4 __attribute__((ext_vector_type(4)));
typedef float f32x4  __attribute__((ext_vector_type(4)));

__device__ __forceinline__ float lrelu(float x){ return x > 0.f ? x : 0.2f*x; }

__device__ __forceinline__ unsigned short bf16_rne(float f){
    unsigned u = __float_as_uint(f);
    unsigned r = u + 0x7FFF + ((u >> 16) & 1);
    return (unsigned short)(r >> 16);
}
__device__ __forceinline__ float bf16f(unsigned short h){
    return __uint_as_float((unsigned)h << 16);
}

// barrier that drains LDS ops but leaves global prefetch loads (vmcnt) in flight
__device__ __forceinline__ void block_sync_lds(){
    asm volatile("s_waitcnt lgkmcnt(0)" ::: "memory");
    __builtin_amdgcn_s_barrier();
    asm volatile("" ::: "memory");
}

// ---------------- CSR build (sort edges by dst) ----------------
__global__ void k_init_counts(int* counts){
    int i = blockIdx.x*256 + threadIdx.x;
    if (i < N_NODES) counts[i] = 1;   // self-loop
}
__global__ void k_count(const int* __restrict__ ei, int* counts){
    int i = blockIdx.x*256 + threadIdx.x;
    if (i < N_EDGES) atomicAdd(&counts[ei[N_EDGES + i]], 1);
}
__global__ __launch_bounds__(1024) void k_scan(const int* __restrict__ counts,
                                               int* __restrict__ row_start,
                                               int* __restrict__ cursor){
    __shared__ int sd[1024];
    int t = threadIdx.x;
    int v[8]; int sum = 0;
    #pragma unroll
    for (int i=0;i<8;i++){ v[i] = counts[t*8+i]; sum += v[i]; }
    sd[t] = sum; __syncthreads();
    for (int off=1; off<1024; off<<=1){
        int vv = (t >= off) ? sd[t-off] : 0;
        __syncthreads();
        sd[t] += vv;
        __syncthreads();
    }
    int run = sd[t] - sum;  // exclusive prefix
    #pragma unroll
    for (int i=0;i<8;i++){ row_start[t*8+i] = run; cursor[t*8+i] = run; run += v[i]; }
    if (t == 1023) row_start[N_NODES] = run;
}
__global__ void k_fill(const int* __restrict__ ei, int* cursor, int* __restrict__ csr_src){
    int i = blockIdx.x*256 + threadIdx.x;
    if (i >= E_TOT) return;
    int s, d;
    if (i < N_EDGES){ s = ei[i]; d = ei[N_EDGES + i]; }
    else { s = i - N_EDGES; d = s; }
    int pos = atomicAdd(&cursor[d], 1);
    csr_src[pos] = s;
}

// ---- pack W1 fp32 -> split-bf16 B-fragment order: [hg][ks][ct][lane][8] ----
__global__ void k_packw1d(const float* __restrict__ W1,
                          unsigned short* __restrict__ fh, unsigned short* __restrict__ fl){
    int g = blockIdx.x*256 + threadIdx.x;            // 64*4*4*64 = 65536 groups
    int lane = g & 63, ct = (g >> 6) & 3, ks = (g >> 8) & 3, hg = g >> 10;
    int col = hg*64 + ct*16 + (lane & 15);
    int k = ks*32 + (lane >> 4)*8;
    const float* src = W1 + (size_t)col*IN_F + k;
    bf16x8 hv, lv;
    #pragma unroll
    for (int j=0;j<8;j++){
        float f = src[j];
        unsigned short hb = bf16_rne(f);
        hv[j] = (short)hb;
        lv[j] = (short)bf16_rne(f - bf16f(hb));
    }
    *(bf16x8*)(fh + (size_t)g*8) = hv;
    *(bf16x8*)(fl + (size_t)g*8) = lv;
}

// ---- pack W2 fp32 -> split-bf16 B-fragment order: [kc][ni][lane][8] ----
__global__ void k_packw2d(const float* __restrict__ W2,
                          unsigned short* __restrict__ fh, unsigned short* __restrict__ fl){
    int g = blockIdx.x*256 + threadIdx.x;            // 128*10*64 = 81920 groups
    int lane = g & 63, ni = (g >> 6) % 10, kc = g / 640;
    int n = ni*16 + (lane & 15);
    int k = kc*32 + (lane >> 4)*8;
    const float* src = W2 + (size_t)n*F1 + k;
    bf16x8 hv, lv;
    #pragma unroll
    for (int j=0;j<8;j++){
        float f = src[j];
        unsigned short hb = bf16_rne(f);
        hv[j] = (short)hb;
        lv[j] = (short)bf16_rne(f - bf16f(hb));
    }
    *(bf16x8*)(fh + (size_t)g*8) = hv;
    *(bf16x8*)(fl + (size_t)g*8) = lv;
}

// ------- attention vectors: vsT[k][h] = sum_c a_s[h,c] * W1[h*64+c, k] -------
__global__ __launch_bounds__(128) void k_attvec(const float* __restrict__ W1,
        const float* __restrict__ a_s, const float* __restrict__ a_d,
        float* __restrict__ vsT, float* __restrict__ vdT){
    int h = blockIdx.x, k = threadIdx.x;
    float s = 0.f, d = 0.f;
    for (int c = 0; c < HID; c++){
        float w = W1[(size_t)(h*HID + c)*IN_F + k];
        s += a_s[h*HID + c] * w;
        d += a_d[h*HID + c] * w;
    }
    vsT[k*NH1 + h] = s;
    vdT[k*NH1 + h] = d;
}

// ---------- alpha dots from x: as1[n,h] = x[n,:] . vsT[:,h] ------------------
__global__ __launch_bounds__(128) void k_alpha1x(const float* __restrict__ x,
        const float* __restrict__ vsT, const float* __restrict__ vdT,
        float* __restrict__ as1, float* __restrict__ ad1){
    int n = blockIdx.x, t = threadIdx.x;
    __shared__ float xs[IN_F];
    xs[t] = x[(size_t)n*IN_F + t];
    __syncthreads();
    if (t < NH1){
        float s = 0.f, d = 0.f;
        for (int k = 0; k < IN_F; k++){
            float xv = xs[k];
            s += xv * vsT[k*NH1 + t];
            d += xv * vdT[k*NH1 + t];
        }
        as1[n*NH1 + t] = s;
        ad1[n*NH1 + t] = d;
    }
}

// ------- x-space aggregation, ALL 64 heads, denom fused, single dispatch -----
__global__ __launch_bounds__(256) void k_aggx64(const float* __restrict__ x,
        const float* __restrict__ as1, const float* __restrict__ ad1,
        const int* __restrict__ row_start, const int* __restrict__ csr_src,
        unsigned short* __restrict__ txhi){
    int n = blockIdx.x, t = threadIdx.x;
    __shared__ float ad_s[NH1];
    __shared__ float wt[ET][NH1];   // 4 KB
    __shared__ int   st[ET];
    __shared__ float xs[ET][IN_F];  // 8 KB
    int e0 = row_start[n], e1 = row_start[n+1];
    if (t < NH1) ad_s[t] = ad1[n*NH1 + t];
    int hq = t >> 4, f0 = (t & 15)*8;
    float acc[4][8] = {};
    float D[4] = {0.f, 0.f, 0.f, 0.f};
    for (int eb = e0; eb < e1; eb += ET){
        int ne = min(ET, e1 - eb);
        if (t < ne) st[t] = csr_src[eb + t];
        __syncthreads();
        for (int idx = t; idx < ne*32; idx += 256){
            int e = idx >> 5, f4 = idx & 31;
            *(float4*)&xs[e][f4*4] = *(const float4*)(x + (size_t)st[e]*IN_F + f4*4);
        }
        for (int idx = t; idx < ne*NH1; idx += 256){
            int e = idx >> 6, hh = idx & 63;
            wt[e][hh] = expf(lrelu(as1[st[e]*NH1 + hh] + ad_s[hh]));
        }
        __syncthreads();
        for (int e = 0; e < ne; e++){
            float4 v0 = *(const float4*)&xs[e][f0];
            float4 v1 = *(const float4*)&xs[e][f0+4];
            float xv[8] = {v0.x,v0.y,v0.z,v0.w,v1.x,v1.y,v1.z,v1.w};
            #pragma unroll
            for (int c=0;c<4;c++){
                float w = wt[e][hq*4 + c];
                D[c] += w;
                #pragma unroll
                for (int j=0;j<8;j++) acc[c][j] += w*xv[j];
            }
        }
        __syncthreads();
    }
    #pragma unroll
    for (int c=0;c<4;c++){
        float dinv = 1.f / D[c];
        bf16x8 hv;
        #pragma unroll
        for (int j=0;j<8;j++) hv[j] = (short)bf16_rne(acc[c][j] * dinv);
        size_t o = ((size_t)(hq*4 + c)*N_NODES + n)*IN_F + f0;
        *(bf16x8*)(txhi + o) = hv;
    }
}

// ------- FUSED layer-1 projection + ELU + layer-2 projection -----------------
// grid (64 row-blocks, NP=8 head-groups) = 512 blocks -> 2 blocks/CU resident.
// 512 thr = 8 waves (wr = wave>>1 row-pair, wc = wave&1 col-half); 128 rows.
// LDS 68 KB: W1s (hi+lo, 32K) + W2s (hi only, 20K) + X1s (16K, swizzled).
// A fragments read directly from global txhi (L2/L3-hot, 2x wc duplication);
// W2 lo-plane read directly from global (L2-hot, shared by 64 row-blocks).
// W[h+1] prefetched into regs during iter h; vmcnt stays in flight across the
// lgkmcnt-only barriers.
__global__ __launch_bounds__(512, 4) void k_gemm12(
        const unsigned short* __restrict__ txhi,
        const unsigned short* __restrict__ w1fh, const unsigned short* __restrict__ w1fl,
        const unsigned short* __restrict__ w2fh, const unsigned short* __restrict__ w2fl,
        const float* __restrict__ b1,
        float* __restrict__ P){
    __shared__ __attribute__((aligned(16))) unsigned short W1s[16384];  // 32 KB hi|lo
    __shared__ __attribute__((aligned(16))) unsigned short W2s[10240];  // 20 KB hi
    __shared__ __attribute__((aligned(16))) unsigned short X1s[8192];   // 16 KB swizzled

    const int tid  = threadIdx.x;
    const int wave = tid >> 6, lane = tid & 63;
    const int wr = wave >> 1, wc = wave & 1;
    const int q = lane >> 4, l16 = lane & 15;
    const int row0 = blockIdx.x * 128;
    const int g = blockIdx.y;
    const int h0 = g * HG;

    // ---- prologue: prefetch W[h0] into regs ----
    bf16x8 pw1[4], pw2[2]; bf16x4 pw2t;
    {
        #pragma unroll
        for (int r=0;r<2;r++){
            pw1[r]   = *(const bf16x8*)(w1fh + (size_t)h0*8192 + r*4096 + tid*8);
            pw1[2+r] = *(const bf16x8*)(w1fl + (size_t)h0*8192 + r*4096 + tid*8);
            pw2[r]   = *(const bf16x8*)(w2fh + (size_t)h0*10240 + r*4096 + tid*8);
        }
        pw2t = *(const bf16x4*)(w2fh + (size_t)h0*10240 + 8192 + tid*4);
    }

    f32x4 acc2[2][5] = {};

    #pragma unroll 1
    for (int hh = 0; hh < HG; hh++){
        const int h = h0 + hh;
        block_sync_lds();                       // B_top: prev GEMM2 LDS reads done
        // ---- write W[h] from prefetch regs ----
        #pragma unroll
        for (int r=0;r<4;r++) *(bf16x8*)&W1s[r*4096 + tid*8] = pw1[r];
        #pragma unroll
        for (int r=0;r<2;r++) *(bf16x8*)&W2s[r*4096 + tid*8] = pw2[r];
        *(bf16x4*)&W2s[8192 + tid*4] = pw2t;
        // ---- issue prefetch of W[h+1] (stays in flight across barriers) ----
        const int hn = (hh+1 < HG) ? (h+1) : h;
        {
            #pragma unroll
            for (int r=0;r<2;r++){
                pw1[r]   = *(const bf16x8*)(w1fh + (size_t)hn*8192 + r*4096 + tid*8);
                pw1[2+r] = *(const bf16x8*)(w1fl + (size_t)hn*8192 + r*4096 + tid*8);
                pw2[r]   = *(const bf16x8*)(w2fh + (size_t)hn*10240 + r*4096 + tid*8);
            }
            pw2t = *(const bf16x4*)(w2fh + (size_t)hn*10240 + 8192 + tid*4);
        }
        block_sync_lds();                       // B_mid: W[h] visible
        // ---- GEMM1: X1 = A[h] @ W1[h]^T; A direct from global ----
        const unsigned short* Abase = txhi + ((size_t)h*N_NODES + row0)*IN_F;
        f32x4 c1[2][2] = {};
        #pragma unroll
        for (int ks=0;ks<4;ks++){
            bf16x8 af[2];
            #pragma unroll
            for (int mi=0;mi<2;mi++){
                int row = (2*wr+mi)*16 + l16;
                af[mi] = *(const bf16x8*)(Abase + (size_t)row*IN_F + ks*32 + q*8);
            }
            bf16x8 bh[2], bl[2];
            #pragma unroll
            for (int ni=0;ni<2;ni++){
                int f = (ks*4 + 2*wc + ni)*512 + lane*8;
                bh[ni] = *(const bf16x8*)&W1s[f];
                bl[ni] = *(const bf16x8*)&W1s[8192 + f];
            }
            #pragma unroll
            for (int mi=0;mi<2;mi++)
                #pragma unroll
                for (int ni=0;ni<2;ni++){
                    c1[mi][ni] = __builtin_amdgcn_mfma_f32_16x16x32_bf16(af[mi], bh[ni], c1[mi][ni], 0,0,0);
                    c1[mi][ni] = __builtin_amdgcn_mfma_f32_16x16x32_bf16(af[mi], bl[ni], c1[mi][ni], 0,0,0);
                }
        }
        // ---- bias + ELU -> X1s (swizzled bf16); WAR-safe (prev reads done at B_top)
        #pragma unroll
        for (int ni=0;ni<2;ni++){
            int col = (2*wc+ni)*16 + l16;
            float b = b1[h*64 + col];
            #pragma unroll
            for (int mi=0;mi<2;mi++){
                #pragma unroll
                for (int i=0;i<4;i++){
                    float v = c1[mi][ni][i] + b;
                    float o = v > 0.f ? v : expm1f(v);
                    int row = (2*wr+mi)*16 + q*4 + i;
                    int sidx = (row*64 + col) ^ ((row & 7) << 3);
                    X1s[sidx] = bf16_rne(o);
                }
            }
        }
        block_sync_lds();                       // B_vis: X1 visible
        // ---- GEMM2: acc2 += X1 @ W2[h-slice]^T; hi from LDS, lo from global --
        #pragma unroll
        for (int ks=0;ks<2;ks++){
            bf16x8 a2[2];
            #pragma unroll
            for (int mi=0;mi<2;mi++){
                int row = (2*wr+mi)*16 + l16;
                int sidx = (row*64 + ks*32 + q*8) ^ ((row & 7) << 3);
                a2[mi] = *(const bf16x8*)&X1s[sidx];
            }
            bf16x8 bh[5], bl[5];
            #pragma unroll
            for (int ni=0;ni<5;ni++){
                int f = (ks*10 + wc*5 + ni)*512 + lane*8;
                bh[ni] = *(const bf16x8*)&W2s[f];
                bl[ni] = *(const bf16x8*)(w2fl + (size_t)((h*2 + ks)*10 + wc*5 + ni)*512 + lane*8);
            }
            #pragma unroll
            for (int mi=0;mi<2;mi++)
                #pragma unroll
                for (int ni=0;ni<5;ni++){
                    acc2[mi][ni] = __builtin_amdgcn_mfma_f32_16x16x32_bf16(a2[mi], bh[ni], acc2[mi][ni], 0,0,0);
                    acc2[mi][ni] = __builtin_amdgcn_mfma_f32_16x16x32_bf16(a2[mi], bl[ni], acc2[mi][ni], 0,0,0);
                }
        }
    }

    // ---- epilogue: head-group partial store ----
    float* outp = P + ((size_t)g*N_NODES + row0)*F2;
    #pragma unroll
    for (int mi=0;mi<2;mi++)
        #pragma unroll
        for (int ni=0;ni<5;ni++)
            #pragma unroll
            for (int i=0;i<4;i++){
                int rr = (2*wr+mi)*16 + q*4 + i;
                int cc = wc*80 + ni*16 + l16;
                outp[(size_t)rr*F2 + cc] = acc2[mi][ni][i];
            }
}

// ---------------- reduce NP head-group partials -> h2 ----------------
__global__ __launch_bounds__(256) void k_reduce(const float* __restrict__ P,
                                                float* __restrict__ h2){
    const int NV = N_NODES*F2/4;
    int i = blockIdx.x*256 + threadIdx.x;
    float4 a = ((const float4*)P)[i];
    #pragma unroll
    for (int kb = 1; kb < NP; kb++){
        float4 b = ((const float4*)P)[(size_t)kb*NV + i];
        a.x += b.x; a.y += b.y; a.z += b.z; a.w += b.w;
    }
    ((float4*)h2)[i] = a;
}

// ---------------- attention dots, layer 2 ----------------
__global__ __launch_bounds__(64) void k_alpha2(const float* __restrict__ h2,
        const float* __restrict__ att_s, const float* __restrict__ att_d,
        float* __restrict__ as2, float* __restrict__ ad2){
    int n = blockIdx.x, t = threadIdx.x;
    float ps = 0.f, pd = 0.f;
    if (t < 40){
        float4 h = *(const float4*)(h2 + (size_t)n*F2 + t*4);
        float4 a = ((const float4*)att_s)[t];
        float4 d = ((const float4*)att_d)[t];
        ps = h.x*a.x + h.y*a.y + h.z*a.z + h.w*a.w;
        pd = h.x*d.x + h.y*d.y + h.z*d.z + h.w*d.w;
    }
    ps += __shfl_xor(ps,1); ps += __shfl_xor(ps,2); ps += __shfl_xor(ps,4);
    pd += __shfl_xor(pd,1); pd += __shfl_xor(pd,2); pd += __shfl_xor(pd,4);
    if (t < 40 && (t & 7) == 0){
        as2[n*NH2 + (t>>3)] = ps;
        ad2[n*NH2 + (t>>3)] = pd;
    }
}

// ------- layer-2 softmax + aggregation + head-mean + b2 ----------------------
__global__ __launch_bounds__(256) void k_agg2(const float* __restrict__ h2,
        const float* __restrict__ as2, const float* __restrict__ ad2,
        const int* __restrict__ row_start, const int* __restrict__ csr_src,
        const float* __restrict__ b2, float* __restrict__ x2){
    int n = blockIdx.x, t = threadIdx.x;
    __shared__ float ad_s[NH2], den_s[NH2], sacc[F2];
    int e0 = row_start[n], e1 = row_start[n+1];
    if (t < NH2) ad_s[t] = ad2[n*NH2 + t];
    __syncthreads();
    if (t < NH2){
        float d = 0.f;
        for (int e=e0;e<e1;e++){
            int s = csr_src[e];
            d += expf(lrelu(as2[s*NH2 + t] + ad_s[t]));
        }
        den_s[t] = d;
    }
    __syncthreads();
    if (t < F2){
        int h = t >> 5;
        float adh  = ad_s[h];
        float dinv = 1.f/den_s[h];
        float acc = 0.f;
        for (int e=e0;e<e1;e++){
            int s = csr_src[e];
            float w = expf(lrelu(as2[s*NH2 + h] + adh)) * dinv;
            acc += w * h2[(size_t)s*F2 + t];
        }
        sacc[t] = acc;
    }
    __syncthreads();
    if (t < OUT_F){
        float v = (sacc[t] + sacc[t+32] + sacc[t+64] + sacc[t+96] + sacc[t+128]) * 0.2f + b2[t];
        x2[n*OUT_F + t] = v;
    }
}

// ---------------- bond scores + softmax over 64 bonds ----------------
__global__ __launch_bounds__(64) void k_bond(const float* __restrict__ x2,
        const int* __restrict__ lefts, const int* __restrict__ rights,
        float* __restrict__ out){
    int b = threadIdx.x;
    int L = lefts[b], R = rights[b];
    float s = 0.f;
    #pragma unroll
    for (int c=0;c<OUT_F;c+=4){
        float4 l4 = *(const float4*)(x2 + (size_t)L*OUT_F + c);
        float4 r4 = *(const float4*)(x2 + (size_t)R*OUT_F + c);
        s += l4.x+l4.y+l4.z+l4.w + r4.x+r4.y+r4.z+r4.w;
    }
    float m = s;
    #pragma unroll
    for (int off=1; off<64; off<<=1) m = fmaxf(m, __shfl_xor(m, off));
    float e = expf(s - m);
    float sum = e;
    #pragma unroll
    for (int off=1; off<64; off<<=1) sum += __shfl_xor(sum, off);
    out[b] = e / sum;
}

extern "C" void kernel_launch(void* const* d_in, const int* in_sizes, int n_in,
                              void* d_out, int out_size, void* d_ws, size_t ws_size,
                              hipStream_t stream){
    const float* x      = (const float*)d_in[0];
    const int*   ei     = (const int*)  d_in[1];
    const int*   lefts  = (const int*)  d_in[2];
    const int*   rights = (const int*)  d_in[3];
    const float* W1     = (const float*)d_in[4];
    const float* att_s1 = (const float*)d_in[5];
    const float* att_d1 = (const float*)d_in[6];
    const float* b1     = (const float*)d_in[7];
    const float* W2     = (const float*)d_in[8];
    const float* att_s2 = (const float*)d_in[9];
    const float* att_d2 = (const float*)d_in[10];
    const float* b2     = (const float*)d_in[11];
    float* out = (float*)d_out;

    // fixed layout (txhi 134 MB + partials 42 MB dominate)
    char* ws = (char*)d_ws;
    size_t off = 0;
    auto alloc = [&](size_t bytes) -> void* {
        void* p = ws + off;
        off += (bytes + 255) & ~(size_t)255;
        return p;
    };
    unsigned short* txhi = (unsigned short*)alloc((size_t)NH1*N_NODES*IN_F*2); // 134 MB
    float* part   = (float*)alloc((size_t)NP*N_NODES*F2*4);                    // 42 MB
    float* h2     = (float*)alloc((size_t)N_NODES*F2*4);
    float* as1    = (float*)alloc((size_t)N_NODES*NH1*4);
    float* ad1    = (float*)alloc((size_t)N_NODES*NH1*4);
    float* as2    = (float*)alloc((size_t)N_NODES*NH2*4);
    float* ad2    = (float*)alloc((size_t)N_NODES*NH2*4);
    float* x2     = (float*)alloc((size_t)N_NODES*OUT_F*4);
    float* vsT    = (float*)alloc((size_t)IN_F*NH1*4);
    float* vdT    = (float*)alloc((size_t)IN_F*NH1*4);
    unsigned short* w1fh = (unsigned short*)alloc((size_t)F1*IN_F*2);
    unsigned short* w1fl = (unsigned short*)alloc((size_t)F1*IN_F*2);
    unsigned short* w2fh = (unsigned short*)alloc((size_t)128*10*512*2);
    unsigned short* w2fl = (unsigned short*)alloc((size_t)128*10*512*2);
    int* counts    = (int*)alloc((size_t)N_NODES*4);
    int* row_start = (int*)alloc((size_t)(N_NODES+1)*4);
    int* cursor    = (int*)alloc((size_t)N_NODES*4);
    int* csr_src   = (int*)alloc((size_t)E_TOT*4);

    // CSR by destination
    k_init_counts<<<32, 256, 0, stream>>>(counts);
    k_count<<<192, 256, 0, stream>>>(ei, counts);
    k_scan<<<1, 1024, 0, stream>>>(counts, row_start, cursor);
    k_fill<<<224, 256, 0, stream>>>(ei, cursor, csr_src);

    // fragment-order split-bf16 weight packs (direct from fp32)
    k_packw1d<<<65536/256, 256, 0, stream>>>(W1, w1fh, w1fl);
    k_packw2d<<<81920/256, 256, 0, stream>>>(W2, w2fh, w2fl);

    // alpha dots (once, from x); denominators fused into k_aggx64
    k_attvec<<<NH1, 128, 0, stream>>>(W1, att_s1, att_d1, vsT, vdT);
    k_alpha1x<<<N_NODES, 128, 0, stream>>>(x, vsT, vdT, as1, ad1);

    // layer 1: single-pass aggregation (all heads)
    k_aggx64<<<N_NODES, 256, 0, stream>>>(x, as1, ad1, row_start, csr_src, txhi);

    // FUSED proj1 + ELU + proj2 (head-group partials) + reduce
    k_gemm12<<<dim3(64, NP), 512, 0, stream>>>(txhi, w1fh, w1fl, w2fh, w2fl, b1, part);
    k_reduce<<<N_NODES*F2/4/256, 256, 0, stream>>>(part, h2);

    k_alpha2<<<N_NODES, 64, 0, stream>>>(h2, att_s2, att_d2, as2, ad2);
    k_agg2<<<N_NODES, 256, 0, stream>>>(h2, as2, ad2, row_start, csr_src, b2, x2);

    k_bond<<<1, 64, 0, stream>>>(x2, lefts, rights, out);
}

// Round 4
// 258.262 us; speedup vs baseline: 1.2653x; 1.2653x over previous
//
#include <hip/hip_runtime.h>
#include <hip/hip_bf16.h>
#include <math.h>

#define N_NODES  8192
#define N_EDGES  49152
#define E_TOT    57344   // edges + self-loops
#define IN_F     128
#define HID      64
#define NH1      64
#define NH2      5
#define OUT_F    32
#define F1       4096    // NH1*HID
#define F2       160     // NH2*OUT_F
#define N_BONDS  64
#define ET       16      // aggx edge-tile
#define NP       4       // head-group partials for fused gemm12
#define HG       16      // heads per group = NH1/NP

typedef short bf16x8 __attribute__((ext_vector_type(8)));
typedef float f32x4  __attribute__((ext_vector_type(4)));

__device__ __forceinline__ float lrelu(float x){ return x > 0.f ? x : 0.2f*x; }

__device__ __forceinline__ unsigned short bf16_rne(float f){
    unsigned u = __float_as_uint(f);
    unsigned r = u + 0x7FFF + ((u >> 16) & 1);
    return (unsigned short)(r >> 16);
}
__device__ __forceinline__ float bf16f(unsigned short h){
    return __uint_as_float((unsigned)h << 16);
}

// barrier that drains LDS ops but leaves global loads (vmcnt) in flight
__device__ __forceinline__ void block_sync_lds(){
    asm volatile("s_waitcnt lgkmcnt(0)" ::: "memory");
    __builtin_amdgcn_s_barrier();
    asm volatile("" ::: "memory");
}

// async global->LDS, 16B per lane; LDS dest is the WAVE-UNIFORM chunk base
// (hardware writes base + lane*16; per m104/m108). Global src is per-lane.
__device__ __forceinline__ void gload_lds16(const unsigned short* gp, unsigned short* lp_base){
    __builtin_amdgcn_global_load_lds(
        (const __attribute__((address_space(1))) unsigned int*)(const void*)gp,
        (__attribute__((address_space(3))) unsigned int*)(void*)lp_base,
        16, 0, 0);
}

// ---------------- CSR build (sort edges by dst) ----------------
__global__ void k_init_counts(int* counts){
    int i = blockIdx.x*256 + threadIdx.x;
    if (i < N_NODES) counts[i] = 1;   // self-loop
}
__global__ void k_count(const int* __restrict__ ei, int* counts){
    int i = blockIdx.x*256 + threadIdx.x;
    if (i < N_EDGES) atomicAdd(&counts[ei[N_EDGES + i]], 1);
}
__global__ __launch_bounds__(1024) void k_scan(const int* __restrict__ counts,
                                               int* __restrict__ row_start,
                                               int* __restrict__ cursor){
    __shared__ int sd[1024];
    int t = threadIdx.x;
    int v[8]; int sum = 0;
    #pragma unroll
    for (int i=0;i<8;i++){ v[i] = counts[t*8+i]; sum += v[i]; }
    sd[t] = sum; __syncthreads();
    for (int off=1; off<1024; off<<=1){
        int vv = (t >= off) ? sd[t-off] : 0;
        __syncthreads();
        sd[t] += vv;
        __syncthreads();
    }
    int run = sd[t] - sum;  // exclusive prefix
    #pragma unroll
    for (int i=0;i<8;i++){ row_start[t*8+i] = run; cursor[t*8+i] = run; run += v[i]; }
    if (t == 1023) row_start[N_NODES] = run;
}
__global__ void k_fill(const int* __restrict__ ei, int* cursor, int* __restrict__ csr_src){
    int i = blockIdx.x*256 + threadIdx.x;
    if (i >= E_TOT) return;
    int s, d;
    if (i < N_EDGES){ s = ei[i]; d = ei[N_EDGES + i]; }
    else { s = i - N_EDGES; d = s; }
    int pos = atomicAdd(&cursor[d], 1);
    csr_src[pos] = s;
}

// ---- pack W1 fp32 -> split-bf16 B-fragment order: [hg][ks][ct][lane][8] ----
__global__ void k_packw1d(const float* __restrict__ W1,
                          unsigned short* __restrict__ fh, unsigned short* __restrict__ fl){
    int g = blockIdx.x*256 + threadIdx.x;            // 64*4*4*64 = 65536 groups
    int lane = g & 63, ct = (g >> 6) & 3, ks = (g >> 8) & 3, hg = g >> 10;
    int col = hg*64 + ct*16 + (lane & 15);
    int k = ks*32 + (lane >> 4)*8;
    const float* src = W1 + (size_t)col*IN_F + k;
    bf16x8 hv, lv;
    #pragma unroll
    for (int j=0;j<8;j++){
        float f = src[j];
        unsigned short hb = bf16_rne(f);
        hv[j] = (short)hb;
        lv[j] = (short)bf16_rne(f - bf16f(hb));
    }
    *(bf16x8*)(fh + (size_t)g*8) = hv;
    *(bf16x8*)(fl + (size_t)g*8) = lv;
}

// ---- pack W2 fp32 -> split-bf16 B-fragment order: [kc][ni][lane][8] ----
__global__ void k_packw2d(const float* __restrict__ W2,
                          unsigned short* __restrict__ fh, unsigned short* __restrict__ fl){
    int g = blockIdx.x*256 + threadIdx.x;            // 128*10*64 = 81920 groups
    int lane = g & 63, ni = (g >> 6) % 10, kc = g / 640;
    int n = ni*16 + (lane & 15);
    int k = kc*32 + (lane >> 4)*8;
    const float* src = W2 + (size_t)n*F1 + k;
    bf16x8 hv, lv;
    #pragma unroll
    for (int j=0;j<8;j++){
        float f = src[j];
        unsigned short hb = bf16_rne(f);
        hv[j] = (short)hb;
        lv[j] = (short)bf16_rne(f - bf16f(hb));
    }
    *(bf16x8*)(fh + (size_t)g*8) = hv;
    *(bf16x8*)(fl + (size_t)g*8) = lv;
}

// ------- attention vectors: vsT[k][h] = sum_c a_s[h,c] * W1[h*64+c, k] -------
__global__ __launch_bounds__(128) void k_attvec(const float* __restrict__ W1,
        const float* __restrict__ a_s, const float* __restrict__ a_d,
        float* __restrict__ vsT, float* __restrict__ vdT){
    int h = blockIdx.x, k = threadIdx.x;
    float s = 0.f, d = 0.f;
    for (int c = 0; c < HID; c++){
        float w = W1[(size_t)(h*HID + c)*IN_F + k];
        s += a_s[h*HID + c] * w;
        d += a_d[h*HID + c] * w;
    }
    vsT[k*NH1 + h] = s;
    vdT[k*NH1 + h] = d;
}

// ---------- alpha dots from x: as1[n,h] = x[n,:] . vsT[:,h] ------------------
__global__ __launch_bounds__(128) void k_alpha1x(const float* __restrict__ x,
        const float* __restrict__ vsT, const float* __restrict__ vdT,
        float* __restrict__ as1, float* __restrict__ ad1){
    int n = blockIdx.x, t = threadIdx.x;
    __shared__ float xs[IN_F];
    xs[t] = x[(size_t)n*IN_F + t];
    __syncthreads();
    if (t < NH1){
        float s = 0.f, d = 0.f;
        for (int k = 0; k < IN_F; k++){
            float xv = xs[k];
            s += xv * vsT[k*NH1 + t];
            d += xv * vdT[k*NH1 + t];
        }
        as1[n*NH1 + t] = s;
        ad1[n*NH1 + t] = d;
    }
}

// ------- x-space aggregation, ALL 64 heads, denom fused, single dispatch -----
__global__ __launch_bounds__(256) void k_aggx64(const float* __restrict__ x,
        const float* __restrict__ as1, const float* __restrict__ ad1,
        const int* __restrict__ row_start, const int* __restrict__ csr_src,
        unsigned short* __restrict__ txhi){
    int n = blockIdx.x, t = threadIdx.x;
    __shared__ float ad_s[NH1];
    __shared__ float wt[ET][NH1];   // 4 KB
    __shared__ int   st[ET];
    __shared__ float xs[ET][IN_F];  // 8 KB
    int e0 = row_start[n], e1 = row_start[n+1];
    if (t < NH1) ad_s[t] = ad1[n*NH1 + t];
    int hq = t >> 4, f0 = (t & 15)*8;
    float acc[4][8] = {};
    float D[4] = {0.f, 0.f, 0.f, 0.f};
    for (int eb = e0; eb < e1; eb += ET){
        int ne = min(ET, e1 - eb);
        if (t < ne) st[t] = csr_src[eb + t];
        __syncthreads();
        for (int idx = t; idx < ne*32; idx += 256){
            int e = idx >> 5, f4 = idx & 31;
            *(float4*)&xs[e][f4*4] = *(const float4*)(x + (size_t)st[e]*IN_F + f4*4);
        }
        for (int idx = t; idx < ne*NH1; idx += 256){
            int e = idx >> 6, hh = idx & 63;
            wt[e][hh] = expf(lrelu(as1[st[e]*NH1 + hh] + ad_s[hh]));
        }
        __syncthreads();
        for (int e = 0; e < ne; e++){
            float4 v0 = *(const float4*)&xs[e][f0];
            float4 v1 = *(const float4*)&xs[e][f0+4];
            float xv[8] = {v0.x,v0.y,v0.z,v0.w,v1.x,v1.y,v1.z,v1.w};
            #pragma unroll
            for (int c=0;c<4;c++){
                float w = wt[e][hq*4 + c];
                D[c] += w;
                #pragma unroll
                for (int j=0;j<8;j++) acc[c][j] += w*xv[j];
            }
        }
        __syncthreads();
    }
    #pragma unroll
    for (int c=0;c<4;c++){
        float dinv = 1.f / D[c];
        bf16x8 hv;
        #pragma unroll
        for (int j=0;j<8;j++) hv[j] = (short)bf16_rne(acc[c][j] * dinv);
        size_t o = ((size_t)(hq*4 + c)*N_NODES + n)*IN_F + f0;
        *(bf16x8*)(txhi + o) = hv;
    }
}

// ------- FUSED layer-1 projection + ELU + layer-2 projection -----------------
// grid (128 row-blocks, NP=4 head-groups) = 512 blocks; 80 KB LDS + <=128 VGPR
// -> 2 blocks/CU (16 waves/CU, 4/SIMD). 64 rows/block, HG=16 heads.
// All MFMA operands from LDS/regs. Staging via global_load_lds (dest =
// wave-uniform 1KB chunk base; HW adds lane*16):
//   B_vis(h): issue A(h+1)+W1hi(h+1) (4/wave, fly across GEMM2 + 2 barriers)
//   B_top(h+1): issue W2 hi+lo (5/wave) then w1lo reg loads (8/lane)
//   vmcnt(8) (staging done, w1lo still in flight) -> B_mid -> GEMM1 -> ELU ->
//   B_vis -> GEMM2 (all LDS).
__global__ __launch_bounds__(512, 4) void k_gemm12(
        const unsigned short* __restrict__ txhi,
        const unsigned short* __restrict__ w1fh, const unsigned short* __restrict__ w1fl,
        const unsigned short* __restrict__ w2fh, const unsigned short* __restrict__ w2fl,
        const float* __restrict__ b1,
        float* __restrict__ P){
    __shared__ __attribute__((aligned(16))) unsigned short Als[8192];   // 16 KB A tile (64x128, XOR-swizzled)
    __shared__ __attribute__((aligned(16))) unsigned short W1sh[8192];  // 16 KB W1 hi-plane frags
    __shared__ __attribute__((aligned(16))) unsigned short W2s[20480];  // 40 KB W2 hi(0..10240)+lo frags
    __shared__ __attribute__((aligned(16))) unsigned short X1s[4096];   //  8 KB X1 tile (64x64, XOR-swizzled)

    const int tid  = threadIdx.x;
    const int wave = tid >> 6, lane = tid & 63;
    const int wr = wave >> 1, wc = wave & 1;
    const int q = lane >> 4, l16 = lane & 15;
    const int row0 = blockIdx.x * 64;
    const int g = blockIdx.y;
    const int h0 = g * HG;

    // ---- prologue: stage A(h0) + W1hi(h0) (4 issues/wave) ----
    {
        const unsigned short* Ab = txhi + ((size_t)h0*N_NODES + row0)*IN_F;
        const unsigned short* W1b = w1fh + (size_t)h0*8192;
        #pragma unroll
        for (int j=0;j<2;j++){
            int idx = j*8 + wave;
            int eo = idx*512 + lane*8;
            int row = eo >> 7;
            int se = (eo & ~127) | ((eo & 127) ^ ((row & 7) << 3));
            gload_lds16(Ab + se, &Als[idx*512]);
        }
        #pragma unroll
        for (int j=0;j<2;j++){
            int idx = j*8 + wave;
            gload_lds16(W1b + idx*512 + lane*8, &W1sh[idx*512]);
        }
    }

    f32x4 acc2[5] = {};
    bf16x8 wlo[8];

    #pragma unroll 1
    for (int hh = 0; hh < HG; hh++){
        const int h = h0 + hh;
        block_sync_lds();                       // B_top: prev GEMM2 done with W2s/X1s
        // ---- stage W2 hi+lo for h (5 issues/wave) ----
        {
            const unsigned short* W2bh = w2fh + (size_t)h*10240;
            const unsigned short* W2bl = w2fl + (size_t)h*10240;
            #pragma unroll
            for (int j=0;j<5;j++){
                int idx = j*8 + wave;             // 0..39 (idx<20 -> hi plane)
                const unsigned short* src = (idx < 20) ? (W2bh + idx*512 + lane*8)
                                                       : (W2bl + (idx-20)*512 + lane*8);
                gload_lds16(src, &W2s[idx*512]);
            }
        }
        asm volatile("" ::: "memory");          // pin: staging issued before wlo loads
        // ---- W1 lo-plane fragments for this wave -> regs (8 loads/lane) ----
        {
            const unsigned short* W1lb = w1fl + (size_t)h*8192;
            #pragma unroll
            for (int ks=0;ks<4;ks++)
                #pragma unroll
                for (int ni=0;ni<2;ni++)
                    wlo[ks*2+ni] = *(const bf16x8*)(W1lb + (size_t)(ks*4 + 2*wc + ni)*512 + lane*8);
        }
        asm volatile("s_waitcnt vmcnt(8)" ::: "memory");  // A,W1hi,W2 staged; wlo in flight
        __builtin_amdgcn_s_barrier();           // B_mid: LDS staging visible to all
        // ---- GEMM1: X1 = A[h] @ W1[h]^T (hi from LDS, lo from regs) ----
        const int arow = wr*16 + l16;
        f32x4 c1[2] = {};
        #pragma unroll
        for (int ks=0;ks<4;ks++){
            int sidx = (arow*128 + ks*32 + q*8) ^ ((arow & 7) << 3);
            bf16x8 af = *(const bf16x8*)&Als[sidx];
            #pragma unroll
            for (int ni=0;ni<2;ni++){
                bf16x8 bh = *(const bf16x8*)&W1sh[(ks*4 + 2*wc + ni)*512 + lane*8];
                c1[ni] = __builtin_amdgcn_mfma_f32_16x16x32_bf16(af, bh, c1[ni], 0,0,0);
                c1[ni] = __builtin_amdgcn_mfma_f32_16x16x32_bf16(af, wlo[ks*2+ni], c1[ni], 0,0,0);
            }
        }
        // ---- bias + ELU -> X1s (swizzled bf16) ----
        #pragma unroll
        for (int ni=0;ni<2;ni++){
            int col = (2*wc+ni)*16 + l16;
            float b = b1[h*64 + col];
            #pragma unroll
            for (int i=0;i<4;i++){
                float v = c1[ni][i] + b;
                float o = v > 0.f ? v : expm1f(v);
                int row = wr*16 + q*4 + i;
                int sidx = (row*64 + col) ^ ((row & 7) << 3);
                X1s[sidx] = bf16_rne(o);
            }
        }
        block_sync_lds();                       // B_vis: X1 visible; GEMM1 LDS reads retired
        // ---- stage A(h+1) + W1hi(h+1); loads fly across GEMM2 + barriers ----
        if (hh + 1 < HG){
            const unsigned short* Ab = txhi + ((size_t)(h+1)*N_NODES + row0)*IN_F;
            const unsigned short* W1b = w1fh + (size_t)(h+1)*8192;
            #pragma unroll
            for (int j=0;j<2;j++){
                int idx = j*8 + wave;
                int eo = idx*512 + lane*8;
                int row = eo >> 7;
                int se = (eo & ~127) | ((eo & 127) ^ ((row & 7) << 3));
                gload_lds16(Ab + se, &Als[idx*512]);
            }
            #pragma unroll
            for (int j=0;j<2;j++){
                int idx = j*8 + wave;
                gload_lds16(W1b + idx*512 + lane*8, &W1sh[idx*512]);
            }
        }
        // ---- GEMM2: acc2 += X1 @ W2[h-slice]^T (all LDS) ----
        const int xrow = wr*16 + l16;
        #pragma unroll
        for (int ks=0;ks<2;ks++){
            int sidx = (xrow*64 + ks*32 + q*8) ^ ((xrow & 7) << 3);
            bf16x8 a2 = *(const bf16x8*)&X1s[sidx];
            #pragma unroll
            for (int ni=0;ni<5;ni++){
                int f = (ks*10 + wc*5 + ni)*512 + lane*8;
                bf16x8 bh = *(const bf16x8*)&W2s[f];
                bf16x8 bl = *(const bf16x8*)&W2s[10240 + f];
                acc2[ni] = __builtin_amdgcn_mfma_f32_16x16x32_bf16(a2, bh, acc2[ni], 0,0,0);
                acc2[ni] = __builtin_amdgcn_mfma_f32_16x16x32_bf16(a2, bl, acc2[ni], 0,0,0);
            }
        }
    }

    // ---- epilogue: head-group partial store ----
    float* outp = P + ((size_t)g*N_NODES + row0)*F2;
    #pragma unroll
    for (int ni=0;ni<5;ni++)
        #pragma unroll
        for (int i=0;i<4;i++){
            int rr = wr*16 + q*4 + i;
            int cc = wc*80 + ni*16 + l16;
            outp[(size_t)rr*F2 + cc] = acc2[ni][i];
        }
}

// ---------------- reduce NP head-group partials -> h2 ----------------
__global__ __launch_bounds__(256) void k_reduce(const float* __restrict__ P,
                                                float* __restrict__ h2){
    const int NV = N_NODES*F2/4;
    int i = blockIdx.x*256 + threadIdx.x;
    float4 a = ((const float4*)P)[i];
    #pragma unroll
    for (int kb = 1; kb < NP; kb++){
        float4 b = ((const float4*)P)[(size_t)kb*NV + i];
        a.x += b.x; a.y += b.y; a.z += b.z; a.w += b.w;
    }
    ((float4*)h2)[i] = a;
}

// ---------------- attention dots, layer 2 ----------------
__global__ __launch_bounds__(64) void k_alpha2(const float* __restrict__ h2,
        const float* __restrict__ att_s, const float* __restrict__ att_d,
        float* __restrict__ as2, float* __restrict__ ad2){
    int n = blockIdx.x, t = threadIdx.x;
    float ps = 0.f, pd = 0.f;
    if (t < 40){
        float4 h = *(const float4*)(h2 + (size_t)n*F2 + t*4);
        float4 a = ((const float4*)att_s)[t];
        float4 d = ((const float4*)att_d)[t];
        ps = h.x*a.x + h.y*a.y + h.z*a.z + h.w*a.w;
        pd = h.x*d.x + h.y*d.y + h.z*d.z + h.w*d.w;
    }
    ps += __shfl_xor(ps,1); ps += __shfl_xor(ps,2); ps += __shfl_xor(ps,4);
    pd += __shfl_xor(pd,1); pd += __shfl_xor(pd,2); pd += __shfl_xor(pd,4);
    if (t < 40 && (t & 7) == 0){
        as2[n*NH2 + (t>>3)] = ps;
        ad2[n*NH2 + (t>>3)] = pd;
    }
}

// ------- layer-2 softmax + aggregation + head-mean + b2 ----------------------
__global__ __launch_bounds__(256) void k_agg2(const float* __restrict__ h2,
        const float* __restrict__ as2, const float* __restrict__ ad2,
        const int* __restrict__ row_start, const int* __restrict__ csr_src,
        const float* __restrict__ b2, float* __restrict__ x2){
    int n = blockIdx.x, t = threadIdx.x;
    __shared__ float ad_s[NH2], den_s[NH2], sacc[F2];
    int e0 = row_start[n], e1 = row_start[n+1];
    if (t < NH2) ad_s[t] = ad2[n*NH2 + t];
    __syncthreads();
    if (t < NH2){
        float d = 0.f;
        for (int e=e0;e<e1;e++){
            int s = csr_src[e];
            d += expf(lrelu(as2[s*NH2 + t] + ad_s[t]));
        }
        den_s[t] = d;
    }
    __syncthreads();
    if (t < F2){
        int h = t >> 5;
        float adh  = ad_s[h];
        float dinv = 1.f/den_s[h];
        float acc = 0.f;
        for (int e=e0;e<e1;e++){
            int s = csr_src[e];
            float w = expf(lrelu(as2[s*NH2 + h] + adh)) * dinv;
            acc += w * h2[(size_t)s*F2 + t];
        }
        sacc[t] = acc;
    }
    __syncthreads();
    if (t < OUT_F){
        float v = (sacc[t] + sacc[t+32] + sacc[t+64] + sacc[t+96] + sacc[t+128]) * 0.2f + b2[t];
        x2[n*OUT_F + t] = v;
    }
}

// ---------------- bond scores + softmax over 64 bonds ----------------
__global__ __launch_bounds__(64) void k_bond(const float* __restrict__ x2,
        const int* __restrict__ lefts, const int* __restrict__ rights,
        float* __restrict__ out){
    int b = threadIdx.x;
    int L = lefts[b], R = rights[b];
    float s = 0.f;
    #pragma unroll
    for (int c=0;c<OUT_F;c+=4){
        float4 l4 = *(const float4*)(x2 + (size_t)L*OUT_F + c);
        float4 r4 = *(const float4*)(x2 + (size_t)R*OUT_F + c);
        s += l4.x+l4.y+l4.z+l4.w + r4.x+r4.y+r4.z+r4.w;
    }
    float m = s;
    #pragma unroll
    for (int off=1; off<64; off<<=1) m = fmaxf(m, __shfl_xor(m, off));
    float e = expf(s - m);
    float sum = e;
    #pragma unroll
    for (int off=1; off<64; off<<=1) sum += __shfl_xor(sum, off);
    out[b] = e / sum;
}

extern "C" void kernel_launch(void* const* d_in, const int* in_sizes, int n_in,
                              void* d_out, int out_size, void* d_ws, size_t ws_size,
                              hipStream_t stream){
    const float* x      = (const float*)d_in[0];
    const int*   ei     = (const int*)  d_in[1];
    const int*   lefts  = (const int*)  d_in[2];
    const int*   rights = (const int*)  d_in[3];
    const float* W1     = (const float*)d_in[4];
    const float* att_s1 = (const float*)d_in[5];
    const float* att_d1 = (const float*)d_in[6];
    const float* b1     = (const float*)d_in[7];
    const float* W2     = (const float*)d_in[8];
    const float* att_s2 = (const float*)d_in[9];
    const float* att_d2 = (const float*)d_in[10];
    const float* b2     = (const float*)d_in[11];
    float* out = (float*)d_out;

    // fixed layout (txhi 134 MB dominates)
    char* ws = (char*)d_ws;
    size_t off = 0;
    auto alloc = [&](size_t bytes) -> void* {
        void* p = ws + off;
        off += (bytes + 255) & ~(size_t)255;
        return p;
    };
    unsigned short* txhi = (unsigned short*)alloc((size_t)NH1*N_NODES*IN_F*2); // 134 MB
    float* part   = (float*)alloc((size_t)NP*N_NODES*F2*4);                    // 21 MB
    float* h2     = (float*)alloc((size_t)N_NODES*F2*4);
    float* as1    = (float*)alloc((size_t)N_NODES*NH1*4);
    float* ad1    = (float*)alloc((size_t)N_NODES*NH1*4);
    float* as2    = (float*)alloc((size_t)N_NODES*NH2*4);
    float* ad2    = (float*)alloc((size_t)N_NODES*NH2*4);
    float* x2     = (float*)alloc((size_t)N_NODES*OUT_F*4);
    float* vsT    = (float*)alloc((size_t)IN_F*NH1*4);
    float* vdT    = (float*)alloc((size_t)IN_F*NH1*4);
    unsigned short* w1fh = (unsigned short*)alloc((size_t)F1*IN_F*2);
    unsigned short* w1fl = (unsigned short*)alloc((size_t)F1*IN_F*2);
    unsigned short* w2fh = (unsigned short*)alloc((size_t)128*10*512*2);
    unsigned short* w2fl = (unsigned short*)alloc((size_t)128*10*512*2);
    int* counts    = (int*)alloc((size_t)N_NODES*4);
    int* row_start = (int*)alloc((size_t)(N_NODES+1)*4);
    int* cursor    = (int*)alloc((size_t)N_NODES*4);
    int* csr_src   = (int*)alloc((size_t)E_TOT*4);

    // CSR by destination
    k_init_counts<<<32, 256, 0, stream>>>(counts);
    k_count<<<192, 256, 0, stream>>>(ei, counts);
    k_scan<<<1, 1024, 0, stream>>>(counts, row_start, cursor);
    k_fill<<<224, 256, 0, stream>>>(ei, cursor, csr_src);

    // fragment-order split-bf16 weight packs (direct from fp32)
    k_packw1d<<<65536/256, 256, 0, stream>>>(W1, w1fh, w1fl);
    k_packw2d<<<81920/256, 256, 0, stream>>>(W2, w2fh, w2fl);

    // alpha dots (once, from x); denominators fused into k_aggx64
    k_attvec<<<NH1, 128, 0, stream>>>(W1, att_s1, att_d1, vsT, vdT);
    k_alpha1x<<<N_NODES, 128, 0, stream>>>(x, vsT, vdT, as1, ad1);

    // layer 1: single-pass aggregation (all heads)
    k_aggx64<<<N_NODES, 256, 0, stream>>>(x, as1, ad1, row_start, csr_src, txhi);

    // FUSED proj1 + ELU + proj2 (head-group partials) + reduce
    k_gemm12<<<dim3(128, NP), 512, 0, stream>>>(txhi, w1fh, w1fl, w2fh, w2fl, b1, part);
    k_reduce<<<N_NODES*F2/4/256, 256, 0, stream>>>(part, h2);

    k_alpha2<<<N_NODES, 64, 0, stream>>>(h2, att_s2, att_d2, as2, ad2);
    k_agg2<<<N_NODES, 256, 0, stream>>>(h2, as2, ad2, row_start, csr_src, b2, x2);

    k_bond<<<1, 64, 0, stream>>>(x2, lefts, rights, out);
}

// Round 5
// 241.652 us; speedup vs baseline: 1.3523x; 1.0687x over previous
//
#include <hip/hip_runtime.h>
#include <hip/hip_bf16.h>
#include <math.h>

#define N_NODES  8192
#define N_EDGES  49152
#define E_TOT    57344   // edges + self-loops
#define IN_F     128
#define HID      64
#define NH1      64
#define NH2      5
#define OUT_F    32
#define F1       4096    // NH1*HID
#define F2       160     // NH2*OUT_F
#define N_BONDS  64
#define ET       16      // aggx edge-tile
#define NP       4       // head-group partials for fused gemm12
#define HG       16      // heads per group = NH1/NP

typedef short bf16x8 __attribute__((ext_vector_type(8)));
typedef float f32x4  __attribute__((ext_vector_type(4)));

__device__ __forceinline__ float lrelu(float x){ return x > 0.f ? x : 0.2f*x; }

__device__ __forceinline__ unsigned short bf16_rne(float f){
    unsigned u = __float_as_uint(f);
    unsigned r = u + 0x7FFF + ((u >> 16) & 1);
    return (unsigned short)(r >> 16);
}
__device__ __forceinline__ float bf16f(unsigned short h){
    return __uint_as_float((unsigned)h << 16);
}

// barrier that drains LDS ops but leaves global loads (vmcnt) in flight
__device__ __forceinline__ void block_sync_lds(){
    asm volatile("s_waitcnt lgkmcnt(0)" ::: "memory");
    __builtin_amdgcn_s_barrier();
    asm volatile("" ::: "memory");
}

// async global->LDS, 16B per lane; LDS dest is the WAVE-UNIFORM chunk base
// (hardware writes base + lane*16). Global src is per-lane.
__device__ __forceinline__ void gload_lds16(const unsigned short* gp, unsigned short* lp_base){
    __builtin_amdgcn_global_load_lds(
        (const __attribute__((address_space(1))) unsigned int*)(const void*)gp,
        (__attribute__((address_space(3))) unsigned int*)(void*)lp_base,
        16, 0, 0);
}

// ---------------- CSR build (sort edges by dst) ----------------
__global__ void k_init_counts(int* counts){
    int i = blockIdx.x*256 + threadIdx.x;
    if (i < N_NODES) counts[i] = 1;   // self-loop
}
__global__ void k_count(const int* __restrict__ ei, int* counts){
    int i = blockIdx.x*256 + threadIdx.x;
    if (i < N_EDGES) atomicAdd(&counts[ei[N_EDGES + i]], 1);
}
__global__ __launch_bounds__(1024) void k_scan(const int* __restrict__ counts,
                                               int* __restrict__ row_start,
                                               int* __restrict__ cursor){
    __shared__ int sd[1024];
    int t = threadIdx.x;
    int v[8]; int sum = 0;
    #pragma unroll
    for (int i=0;i<8;i++){ v[i] = counts[t*8+i]; sum += v[i]; }
    sd[t] = sum; __syncthreads();
    for (int off=1; off<1024; off<<=1){
        int vv = (t >= off) ? sd[t-off] : 0;
        __syncthreads();
        sd[t] += vv;
        __syncthreads();
    }
    int run = sd[t] - sum;  // exclusive prefix
    #pragma unroll
    for (int i=0;i<8;i++){ row_start[t*8+i] = run; cursor[t*8+i] = run; run += v[i]; }
    if (t == 1023) row_start[N_NODES] = run;
}
__global__ void k_fill(const int* __restrict__ ei, int* cursor, int* __restrict__ csr_src){
    int i = blockIdx.x*256 + threadIdx.x;
    if (i >= E_TOT) return;
    int s, d;
    if (i < N_EDGES){ s = ei[i]; d = ei[N_EDGES + i]; }
    else { s = i - N_EDGES; d = s; }
    int pos = atomicAdd(&cursor[d], 1);
    csr_src[pos] = s;
}

// ---- pack W1 fp32 -> split-bf16 B-fragment order: [hg][ks][ct][lane][8] ----
__global__ void k_packw1d(const float* __restrict__ W1,
                          unsigned short* __restrict__ fh, unsigned short* __restrict__ fl){
    int g = blockIdx.x*256 + threadIdx.x;            // 64*4*4*64 = 65536 groups
    int lane = g & 63, ct = (g >> 6) & 3, ks = (g >> 8) & 3, hg = g >> 10;
    int col = hg*64 + ct*16 + (lane & 15);
    int k = ks*32 + (lane >> 4)*8;
    const float* src = W1 + (size_t)col*IN_F + k;
    bf16x8 hv, lv;
    #pragma unroll
    for (int j=0;j<8;j++){
        float f = src[j];
        unsigned short hb = bf16_rne(f);
        hv[j] = (short)hb;
        lv[j] = (short)bf16_rne(f - bf16f(hb));
    }
    *(bf16x8*)(fh + (size_t)g*8) = hv;
    *(bf16x8*)(fl + (size_t)g*8) = lv;
}

// ---- pack W2 fp32 -> split-bf16 B-fragment order: [kc][ni][lane][8] ----
__global__ void k_packw2d(const float* __restrict__ W2,
                          unsigned short* __restrict__ fh, unsigned short* __restrict__ fl){
    int g = blockIdx.x*256 + threadIdx.x;            // 128*10*64 = 81920 groups
    int lane = g & 63, ni = (g >> 6) % 10, kc = g / 640;
    int n = ni*16 + (lane & 15);
    int k = kc*32 + (lane >> 4)*8;
    const float* src = W2 + (size_t)n*F1 + k;
    bf16x8 hv, lv;
    #pragma unroll
    for (int j=0;j<8;j++){
        float f = src[j];
        unsigned short hb = bf16_rne(f);
        hv[j] = (short)hb;
        lv[j] = (short)bf16_rne(f - bf16f(hb));
    }
    *(bf16x8*)(fh + (size_t)g*8) = hv;
    *(bf16x8*)(fl + (size_t)g*8) = lv;
}

// ------- attention vectors: vsT[k][h] = sum_c a_s[h,c] * W1[h*64+c, k] -------
__global__ __launch_bounds__(128) void k_attvec(const float* __restrict__ W1,
        const float* __restrict__ a_s, const float* __restrict__ a_d,
        float* __restrict__ vsT, float* __restrict__ vdT){
    int h = blockIdx.x, k = threadIdx.x;
    float s = 0.f, d = 0.f;
    for (int c = 0; c < HID; c++){
        float w = W1[(size_t)(h*HID + c)*IN_F + k];
        s += a_s[h*HID + c] * w;
        d += a_d[h*HID + c] * w;
    }
    vsT[k*NH1 + h] = s;
    vdT[k*NH1 + h] = d;
}

// ---------- alpha dots from x: as1[n,h] = x[n,:] . vsT[:,h] ------------------
__global__ __launch_bounds__(128) void k_alpha1x(const float* __restrict__ x,
        const float* __restrict__ vsT, const float* __restrict__ vdT,
        float* __restrict__ as1, float* __restrict__ ad1){
    int n = blockIdx.x, t = threadIdx.x;
    __shared__ float xs[IN_F];
    xs[t] = x[(size_t)n*IN_F + t];
    __syncthreads();
    if (t < NH1){
        float s = 0.f, d = 0.f;
        for (int k = 0; k < IN_F; k++){
            float xv = xs[k];
            s += xv * vsT[k*NH1 + t];
            d += xv * vdT[k*NH1 + t];
        }
        as1[n*NH1 + t] = s;
        ad1[n*NH1 + t] = d;
    }
}

// ------- x-space aggregation, ALL 64 heads, denom fused, single dispatch -----
__global__ __launch_bounds__(256) void k_aggx64(const float* __restrict__ x,
        const float* __restrict__ as1, const float* __restrict__ ad1,
        const int* __restrict__ row_start, const int* __restrict__ csr_src,
        unsigned short* __restrict__ txhi){
    int n = blockIdx.x, t = threadIdx.x;
    __shared__ float ad_s[NH1];
    __shared__ float wt[ET][NH1];   // 4 KB
    __shared__ int   st[ET];
    __shared__ float xs[ET][IN_F];  // 8 KB
    int e0 = row_start[n], e1 = row_start[n+1];
    if (t < NH1) ad_s[t] = ad1[n*NH1 + t];
    int hq = t >> 4, f0 = (t & 15)*8;
    float acc[4][8] = {};
    float D[4] = {0.f, 0.f, 0.f, 0.f};
    for (int eb = e0; eb < e1; eb += ET){
        int ne = min(ET, e1 - eb);
        if (t < ne) st[t] = csr_src[eb + t];
        __syncthreads();
        for (int idx = t; idx < ne*32; idx += 256){
            int e = idx >> 5, f4 = idx & 31;
            *(float4*)&xs[e][f4*4] = *(const float4*)(x + (size_t)st[e]*IN_F + f4*4);
        }
        for (int idx = t; idx < ne*NH1; idx += 256){
            int e = idx >> 6, hh = idx & 63;
            wt[e][hh] = __expf(lrelu(as1[st[e]*NH1 + hh] + ad_s[hh]));
        }
        __syncthreads();
        for (int e = 0; e < ne; e++){
            float4 v0 = *(const float4*)&xs[e][f0];
            float4 v1 = *(const float4*)&xs[e][f0+4];
            float xv[8] = {v0.x,v0.y,v0.z,v0.w,v1.x,v1.y,v1.z,v1.w};
            #pragma unroll
            for (int c=0;c<4;c++){
                float w = wt[e][hq*4 + c];
                D[c] += w;
                #pragma unroll
                for (int j=0;j<8;j++) acc[c][j] += w*xv[j];
            }
        }
        __syncthreads();
    }
    #pragma unroll
    for (int c=0;c<4;c++){
        float dinv = 1.f / D[c];
        bf16x8 hv;
        #pragma unroll
        for (int j=0;j<8;j++) hv[j] = (short)bf16_rne(acc[c][j] * dinv);
        size_t o = ((size_t)(hq*4 + c)*N_NODES + n)*IN_F + f0;
        *(bf16x8*)(txhi + o) = hv;
    }
}

// ------- FUSED layer-1 projection + ELU + layer-2 projection -----------------
// grid (128 row-blocks, NP=4 head-groups) = 512 blocks; 80 KB LDS + 64 VGPR
// -> 2 blocks/CU (16 waves/CU, 4/SIMD). 64 rows/block, HG=16 heads.
// Counted-vmcnt schedule (issue order is load-bearing):
//   B_top -> wlo(8 reg loads) -> W2 staging(5) -> vmcnt(13) [drains only
//   A/W1hi staged last iter] -> B_mid -> GEMM1 (compiler waits wlo at
//   vmcnt(5); W2 stays in flight) -> ELU -> vmcnt(0)+lgkmcnt(0) [W2 drained
//   under GEMM1+ELU shadow] -> B_vis -> stage A/W1hi(h+1) -> GEMM2 (all LDS).
__global__ __launch_bounds__(512, 4) void k_gemm12(
        const unsigned short* __restrict__ txhi,
        const unsigned short* __restrict__ w1fh, const unsigned short* __restrict__ w1fl,
        const unsigned short* __restrict__ w2fh, const unsigned short* __restrict__ w2fl,
        const float* __restrict__ b1,
        float* __restrict__ P){
    __shared__ __attribute__((aligned(16))) unsigned short Als[8192];   // 16 KB A tile (64x128, XOR-swizzled)
    __shared__ __attribute__((aligned(16))) unsigned short W1sh[8192];  // 16 KB W1 hi-plane frags
    __shared__ __attribute__((aligned(16))) unsigned short W2s[20480];  // 40 KB W2 hi(0..10240)+lo frags
    __shared__ __attribute__((aligned(16))) unsigned short X1s[4096];   //  8 KB X1 tile (64x64, XOR-swizzled)

    const int tid  = threadIdx.x;
    const int wave = tid >> 6, lane = tid & 63;
    const int wr = wave >> 1, wc = wave & 1;
    const int q = lane >> 4, l16 = lane & 15;
    const int row0 = blockIdx.x * 64;
    const int g = blockIdx.y;
    const int h0 = g * HG;

    // ---- prologue: stage A(h0) + W1hi(h0) (4 issues/wave) ----
    {
        const unsigned short* Ab = txhi + ((size_t)h0*N_NODES + row0)*IN_F;
        const unsigned short* W1b = w1fh + (size_t)h0*8192;
        #pragma unroll
        for (int j=0;j<2;j++){
            int idx = j*8 + wave;
            int eo = idx*512 + lane*8;
            int row = eo >> 7;
            int se = (eo & ~127) | ((eo & 127) ^ ((row & 7) << 3));
            gload_lds16(Ab + se, &Als[idx*512]);
        }
        #pragma unroll
        for (int j=0;j<2;j++){
            int idx = j*8 + wave;
            gload_lds16(W1b + idx*512 + lane*8, &W1sh[idx*512]);
        }
    }

    f32x4 acc2[5] = {};
    bf16x8 wlo[8];

    #pragma unroll 1
    for (int hh = 0; hh < HG; hh++){
        const int h = h0 + hh;
        block_sync_lds();                       // B_top: prev GEMM2 done with W2s/X1s
        // ---- W1 lo-plane fragments -> regs FIRST (oldest after staged A/W1hi) ----
        {
            const unsigned short* W1lb = w1fl + (size_t)h*8192;
            #pragma unroll
            for (int ks=0;ks<4;ks++)
                #pragma unroll
                for (int ni=0;ni<2;ni++)
                    wlo[ks*2+ni] = *(const bf16x8*)(W1lb + (size_t)(ks*4 + 2*wc + ni)*512 + lane*8);
        }
        asm volatile("" ::: "memory");          // pin: wlo issued before W2 staging
        // ---- stage W2 hi+lo for h (5 issues/wave) ----
        {
            const unsigned short* W2bh = w2fh + (size_t)h*10240;
            const unsigned short* W2bl = w2fl + (size_t)h*10240;
            #pragma unroll
            for (int j=0;j<5;j++){
                int idx = j*8 + wave;             // 0..39 (idx<20 -> hi plane)
                const unsigned short* src = (idx < 20) ? (W2bh + idx*512 + lane*8)
                                                       : (W2bl + (idx-20)*512 + lane*8);
                gload_lds16(src, &W2s[idx*512]);
            }
        }
        // outstanding: A/W1hi(4, oldest) + wlo(8) + W2(5) = 17 -> drain only A/W1hi
        asm volatile("s_waitcnt vmcnt(13)" ::: "memory");
        __builtin_amdgcn_s_barrier();           // B_mid: A/W1hi staging visible
        // ---- GEMM1: X1 = A[h] @ W1[h]^T (hi from LDS, lo from regs) ----
        const int arow = wr*16 + l16;
        f32x4 c1[2] = {};
        __builtin_amdgcn_s_setprio(1);
        #pragma unroll
        for (int ks=0;ks<4;ks++){
            int sidx = (arow*128 + ks*32 + q*8) ^ ((arow & 7) << 3);
            bf16x8 af = *(const bf16x8*)&Als[sidx];
            #pragma unroll
            for (int ni=0;ni<2;ni++){
                bf16x8 bh = *(const bf16x8*)&W1sh[(ks*4 + 2*wc + ni)*512 + lane*8];
                c1[ni] = __builtin_amdgcn_mfma_f32_16x16x32_bf16(af, bh, c1[ni], 0,0,0);
                c1[ni] = __builtin_amdgcn_mfma_f32_16x16x32_bf16(af, wlo[ks*2+ni], c1[ni], 0,0,0);
            }
        }
        __builtin_amdgcn_s_setprio(0);
        // ---- bias + fast ELU -> X1s (swizzled bf16) ----
        #pragma unroll
        for (int ni=0;ni<2;ni++){
            int col = (2*wc+ni)*16 + l16;
            float b = b1[h*64 + col];
            #pragma unroll
            for (int i=0;i<4;i++){
                float v = c1[ni][i] + b;
                float o = v > 0.f ? v : (__expf(v) - 1.f);
                int row = wr*16 + q*4 + i;
                int sidx = (row*64 + col) ^ ((row & 7) << 3);
                X1s[sidx] = bf16_rne(o);
            }
        }
        // drain W2 (only it remains in flight) under the GEMM1+ELU shadow
        asm volatile("s_waitcnt vmcnt(0) lgkmcnt(0)" ::: "memory");
        __builtin_amdgcn_s_barrier();           // B_vis: X1 + W2 staging visible
        // ---- stage A(h+1) + W1hi(h+1); loads fly across GEMM2 + next B_top ----
        if (hh + 1 < HG){
            const unsigned short* Ab = txhi + ((size_t)(h+1)*N_NODES + row0)*IN_F;
            const unsigned short* W1b = w1fh + (size_t)(h+1)*8192;
            #pragma unroll
            for (int j=0;j<2;j++){
                int idx = j*8 + wave;
                int eo = idx*512 + lane*8;
                int row = eo >> 7;
                int se = (eo & ~127) | ((eo & 127) ^ ((row & 7) << 3));
                gload_lds16(Ab + se, &Als[idx*512]);
            }
            #pragma unroll
            for (int j=0;j<2;j++){
                int idx = j*8 + wave;
                gload_lds16(W1b + idx*512 + lane*8, &W1sh[idx*512]);
            }
        }
        // ---- GEMM2: acc2 += X1 @ W2[h-slice]^T (all LDS) ----
        const int xrow = wr*16 + l16;
        __builtin_amdgcn_s_setprio(1);
        #pragma unroll
        for (int ks=0;ks<2;ks++){
            int sidx = (xrow*64 + ks*32 + q*8) ^ ((xrow & 7) << 3);
            bf16x8 a2 = *(const bf16x8*)&X1s[sidx];
            #pragma unroll
            for (int ni=0;ni<5;ni++){
                int f = (ks*10 + wc*5 + ni)*512 + lane*8;
                bf16x8 bh = *(const bf16x8*)&W2s[f];
                bf16x8 bl = *(const bf16x8*)&W2s[10240 + f];
                acc2[ni] = __builtin_amdgcn_mfma_f32_16x16x32_bf16(a2, bh, acc2[ni], 0,0,0);
                acc2[ni] = __builtin_amdgcn_mfma_f32_16x16x32_bf16(a2, bl, acc2[ni], 0,0,0);
            }
        }
        __builtin_amdgcn_s_setprio(0);
    }

    // ---- epilogue: head-group partial store ----
    float* outp = P + ((size_t)g*N_NODES + row0)*F2;
    #pragma unroll
    for (int ni=0;ni<5;ni++)
        #pragma unroll
        for (int i=0;i<4;i++){
            int rr = wr*16 + q*4 + i;
            int cc = wc*80 + ni*16 + l16;
            outp[(size_t)rr*F2 + cc] = acc2[ni][i];
        }
}

// ------- fused: reduce NP partials -> h2 AND layer-2 attention dots ----------
// grid 128 blocks x 256 thr; block = 64 nodes. Phase A: sum partials, write h2,
// stash rows in LDS (padded 164 to avoid same-bank dot reads). Phase B: per
// (node, head) 32-float dots with att_src2/att_dst2.
__global__ __launch_bounds__(256) void k_redalpha(const float* __restrict__ P,
        const float* __restrict__ att_s, const float* __restrict__ att_d,
        float* __restrict__ h2, float* __restrict__ as2, float* __restrict__ ad2){
    __shared__ float hs[64][164];   // 42 KB
    __shared__ float avs[160], avd[160];
    int b = blockIdx.x, t = threadIdx.x;
    int n0 = b*64;
    if (t < 160){ avs[t] = att_s[t]; avd[t] = att_d[t]; }
    const int NV = N_NODES*F2/4;
    int base = b * (64*F2/4);   // float4 index of this block's slab
    #pragma unroll
    for (int v=0; v<10; v++){
        int i = base + v*256 + t;
        float4 a = ((const float4*)P)[i];
        #pragma unroll
        for (int kb=1; kb<NP; kb++){
            float4 bb = ((const float4*)P)[(size_t)kb*NV + i];
            a.x+=bb.x; a.y+=bb.y; a.z+=bb.z; a.w+=bb.w;
        }
        ((float4*)h2)[i] = a;
        int flat = (v*256 + t)*4;          // 0..10236, never crosses a 160-row
        int n = flat / F2, c = flat % F2;
        *(float4*)&hs[n][c] = a;
    }
    __syncthreads();
    for (int idx = t; idx < 320; idx += 256){
        int n = idx/5, hh = idx%5;
        const float* hp = &hs[n][hh*32];
        const float* ap = &avs[hh*32];
        const float* dp = &avd[hh*32];
        float s=0.f, d=0.f;
        #pragma unroll
        for (int c=0;c<32;c++){ float hv=hp[c]; s += hv*ap[c]; d += hv*dp[c]; }
        as2[(n0+n)*NH2 + hh] = s;
        ad2[(n0+n)*NH2 + hh] = d;
    }
}

// ------- layer-2 softmax + aggregation + head-mean + b2 ----------------------
__global__ __launch_bounds__(256) void k_agg2(const float* __restrict__ h2,
        const float* __restrict__ as2, const float* __restrict__ ad2,
        const int* __restrict__ row_start, const int* __restrict__ csr_src,
        const float* __restrict__ b2, float* __restrict__ x2){
    int n = blockIdx.x, t = threadIdx.x;
    __shared__ float ad_s[NH2], den_s[NH2], sacc[F2];
    int e0 = row_start[n], e1 = row_start[n+1];
    if (t < NH2) ad_s[t] = ad2[n*NH2 + t];
    __syncthreads();
    if (t < NH2){
        float d = 0.f;
        for (int e=e0;e<e1;e++){
            int s = csr_src[e];
            d += __expf(lrelu(as2[s*NH2 + t] + ad_s[t]));
        }
        den_s[t] = d;
    }
    __syncthreads();
    if (t < F2){
        int h = t >> 5;
        float adh  = ad_s[h];
        float dinv = 1.f/den_s[h];
        float acc = 0.f;
        for (int e=e0;e<e1;e++){
            int s = csr_src[e];
            float w = __expf(lrelu(as2[s*NH2 + h] + adh)) * dinv;
            acc += w * h2[(size_t)s*F2 + t];
        }
        sacc[t] = acc;
    }
    __syncthreads();
    if (t < OUT_F){
        float v = (sacc[t] + sacc[t+32] + sacc[t+64] + sacc[t+96] + sacc[t+128]) * 0.2f + b2[t];
        x2[n*OUT_F + t] = v;
    }
}

// ---------------- bond scores + softmax over 64 bonds ----------------
__global__ __launch_bounds__(64) void k_bond(const float* __restrict__ x2,
        const int* __restrict__ lefts, const int* __restrict__ rights,
        float* __restrict__ out){
    int b = threadIdx.x;
    int L = lefts[b], R = rights[b];
    float s = 0.f;
    #pragma unroll
    for (int c=0;c<OUT_F;c+=4){
        float4 l4 = *(const float4*)(x2 + (size_t)L*OUT_F + c);
        float4 r4 = *(const float4*)(x2 + (size_t)R*OUT_F + c);
        s += l4.x+l4.y+l4.z+l4.w + r4.x+r4.y+r4.z+r4.w;
    }
    float m = s;
    #pragma unroll
    for (int off=1; off<64; off<<=1) m = fmaxf(m, __shfl_xor(m, off));
    float e = expf(s - m);
    float sum = e;
    #pragma unroll
    for (int off=1; off<64; off<<=1) sum += __shfl_xor(sum, off);
    out[b] = e / sum;
}

extern "C" void kernel_launch(void* const* d_in, const int* in_sizes, int n_in,
                              void* d_out, int out_size, void* d_ws, size_t ws_size,
                              hipStream_t stream){
    const float* x      = (const float*)d_in[0];
    const int*   ei     = (const int*)  d_in[1];
    const int*   lefts  = (const int*)  d_in[2];
    const int*   rights = (const int*)  d_in[3];
    const float* W1     = (const float*)d_in[4];
    const float* att_s1 = (const float*)d_in[5];
    const float* att_d1 = (const float*)d_in[6];
    const float* b1     = (const float*)d_in[7];
    const float* W2     = (const float*)d_in[8];
    const float* att_s2 = (const float*)d_in[9];
    const float* att_d2 = (const float*)d_in[10];
    const float* b2     = (const float*)d_in[11];
    float* out = (float*)d_out;

    // fixed layout (txhi 134 MB dominates)
    char* ws = (char*)d_ws;
    size_t off = 0;
    auto alloc = [&](size_t bytes) -> void* {
        void* p = ws + off;
        off += (bytes + 255) & ~(size_t)255;
        return p;
    };
    unsigned short* txhi = (unsigned short*)alloc((size_t)NH1*N_NODES*IN_F*2); // 134 MB
    float* part   = (float*)alloc((size_t)NP*N_NODES*F2*4);                    // 21 MB
    float* h2     = (float*)alloc((size_t)N_NODES*F2*4);
    float* as1    = (float*)alloc((size_t)N_NODES*NH1*4);
    float* ad1    = (float*)alloc((size_t)N_NODES*NH1*4);
    float* as2    = (float*)alloc((size_t)N_NODES*NH2*4);
    float* ad2    = (float*)alloc((size_t)N_NODES*NH2*4);
    float* x2     = (float*)alloc((size_t)N_NODES*OUT_F*4);
    float* vsT    = (float*)alloc((size_t)IN_F*NH1*4);
    float* vdT    = (float*)alloc((size_t)IN_F*NH1*4);
    unsigned short* w1fh = (unsigned short*)alloc((size_t)F1*IN_F*2);
    unsigned short* w1fl = (unsigned short*)alloc((size_t)F1*IN_F*2);
    unsigned short* w2fh = (unsigned short*)alloc((size_t)128*10*512*2);
    unsigned short* w2fl = (unsigned short*)alloc((size_t)128*10*512*2);
    int* counts    = (int*)alloc((size_t)N_NODES*4);
    int* row_start = (int*)alloc((size_t)(N_NODES+1)*4);
    int* cursor    = (int*)alloc((size_t)N_NODES*4);
    int* csr_src   = (int*)alloc((size_t)E_TOT*4);

    // CSR by destination
    k_init_counts<<<32, 256, 0, stream>>>(counts);
    k_count<<<192, 256, 0, stream>>>(ei, counts);
    k_scan<<<1, 1024, 0, stream>>>(counts, row_start, cursor);
    k_fill<<<224, 256, 0, stream>>>(ei, cursor, csr_src);

    // fragment-order split-bf16 weight packs (direct from fp32)
    k_packw1d<<<65536/256, 256, 0, stream>>>(W1, w1fh, w1fl);
    k_packw2d<<<81920/256, 256, 0, stream>>>(W2, w2fh, w2fl);

    // alpha dots (once, from x); denominators fused into k_aggx64
    k_attvec<<<NH1, 128, 0, stream>>>(W1, att_s1, att_d1, vsT, vdT);
    k_alpha1x<<<N_NODES, 128, 0, stream>>>(x, vsT, vdT, as1, ad1);

    // layer 1: single-pass aggregation (all heads)
    k_aggx64<<<N_NODES, 256, 0, stream>>>(x, as1, ad1, row_start, csr_src, txhi);

    // FUSED proj1 + ELU + proj2 (head-group partials) + fused reduce/alpha2
    k_gemm12<<<dim3(128, NP), 512, 0, stream>>>(txhi, w1fh, w1fl, w2fh, w2fl, b1, part);
    k_redalpha<<<128, 256, 0, stream>>>(part, att_s2, att_d2, h2, as2, ad2);

    k_agg2<<<N_NODES, 256, 0, stream>>>(h2, as2, ad2, row_start, csr_src, b2, x2);

    k_bond<<<1, 64, 0, stream>>>(x2, lefts, rights, out);
}